// Round 10
// baseline (543.376 us; speedup 1.0000x reference)
//
#include <hip/hip_runtime.h>
#include <hip/hip_bf16.h>
#include <math.h>

#define HW 9216      // 96*96
#define C2 64
#define NJC 36       // j-chunk count (grid.y)
#define JTILE 16     // j-tile per lane = 16 accs as 4 x v4
#define EPSN 1e-8f

typedef float v4 __attribute__((ext_vector_type(4)));

// ---------------- kernel 1: compaction (256 threads, shuffle scan) --------
// ilist = positions with mask>=1 (flagged i), jlist = positions with mask<1
__global__ void compact_kernel(const int* __restrict__ mask, int* __restrict__ ilist,
                               int* __restrict__ jlist, int* __restrict__ counts) {
    int t = threadIdx.x;                 // 0..255, each owns 36 consecutive positions
    int base = t * 36;
    unsigned long long fl = 0ull; int cnt = 0;
#pragma unroll
    for (int k = 0; k < 36; k++) {
        int f = (mask[base + k] >= 1) ? 1 : 0;
        fl |= (unsigned long long)f << k;
        cnt += f;
    }
    int lane = t & 63, wave = t >> 6;
    int v = cnt;
#pragma unroll
    for (int off = 1; off < 64; off <<= 1) {
        int u = __shfl_up(v, off, 64);
        if (lane >= off) v += u;
    }
    __shared__ int wsum[4];
    if (lane == 63) wsum[wave] = v;
    __syncthreads();
    int woff = 0;
#pragma unroll
    for (int w = 0; w < 4; w++) if (w < wave) woff += wsum[w];
    int incl = v + woff;
    int excl = incl - cnt;
    int posF = excl, posU = base - excl;
#pragma unroll
    for (int k = 0; k < 36; k++) {
        int p = base + k;
        if ((fl >> k) & 1ull) ilist[posF++] = p; else jlist[posU++] = p;
    }
    if (t == 255) { counts[0] = incl; counts[1] = HW - incl; }
}

// ---------------- kernel 2: build compacted A (row-major) and B (transp) --
// amatR[b][ci][c] = lat[b][c][ilist[ci]]            (contiguous 64f per ci)
// bmatT[b][c][jj] = lat[b][c][jlist[jj]] / max(||lat_j||,eps)
// both zero-padded to HW rows/cols (tails read benign zeros). Zeroes amax.
__global__ void buildab_kernel(const float* __restrict__ x, const int* __restrict__ ilist,
                               const int* __restrict__ jlist, const int* __restrict__ counts,
                               float* __restrict__ amatR, float* __restrict__ bmatT,
                               unsigned long long* __restrict__ amax) {
    int t = blockIdx.x * blockDim.x + threadIdx.x;   // 0 .. 4*HW-1
    if (t >= 4 * HW) return;
    if (t < 2 * HW) amax[t] = 0ull;                  // ws is poisoned 0xAA pre-launch
    int kind = t / (2 * HW);                         // 0 = A, 1 = B
    int r = t - kind * 2 * HW;
    int b = r / HW, p = r - b * HW;
    int n = kind ? counts[1] : counts[0];
    float v[C2] __attribute__((aligned(16)));
    if (p < n) {
        int src = kind ? jlist[p] : ilist[p];
        const float* xl = x + (size_t)(b * 128 + 64) * HW + src;
        float ss = 0.f;
#pragma unroll
        for (int c = 0; c < C2; c++) { float w = xl[(size_t)c * HW]; v[c] = w; ss = fmaf(w, w, ss); }
        if (kind) {
            float inv = 1.0f / fmaxf(sqrtf(ss), EPSN);
#pragma unroll
            for (int c = 0; c < C2; c++) v[c] *= inv;
        }
    } else {
#pragma unroll
        for (int c = 0; c < C2; c++) v[c] = 0.f;
    }
    if (kind) {
        float* d = bmatT + (size_t)b * C2 * HW + p;
#pragma unroll
        for (int c = 0; c < C2; c++) d[(size_t)c * HW] = v[c];
    } else {
        v4* d = (v4*)(amatR + ((size_t)b * HW + p) * C2);
#pragma unroll
        for (int q = 0; q < 16; q++) d[q] = ((const v4*)v)[q];
    }
}

// ordered-float mapping: monotone bijection float -> uint32 under unsigned compare
__device__ __forceinline__ unsigned int ordf(float f) {
    unsigned int u = __float_as_uint(f);
    return (u & 0x80000000u) ? ~u : (u | 0x80000000u);
}

// ---------------- kernel 3: broadcast-B GEMM + argmax (dbuf) --------------
// Lane owns one ci: A (64f) preloaded ONCE into 16 x v4 registers (no VMEM
// in the steady loop); 16 j-accs as 4 x v4 (phrasing that survives regalloc).
// B-tile (64c x 16j = 4 KB) double-buffered in LDS: each thread prefetches
// its single v4 for tile t+1 during compute of tile t -> staging latency
// hidden behind 1024 FMA-cycles. Compute reads Bs with WAVE-UNIFORM
// ds_read_b128 (broadcast, ~free). Per c: 4 LDS + 16 v_fmac -> 89% VALU
// ceiling. First-max tie-break: ascending jb/q/r, strict >, packed-u64
// atomicMax (key = ord(val)<<32 | ~jj).
__global__ __launch_bounds__(256, 4) void gemm_argmax_kernel(
    const float* __restrict__ amatR, const float* __restrict__ bmatT,
    const int* __restrict__ ilist, const int* __restrict__ counts,
    unsigned long long* __restrict__ amax)
{
    __shared__ float Bs[2][C2][JTILE];               // 2 x 4 KB
    int b = blockIdx.z, sc = blockIdx.y;
    int ni = counts[0], nj = counts[1];
    if (blockIdx.x * 256 >= ni) return;              // uniform dead-block exit
    int chunk = (((nj + NJC - 1) / NJC) + 15) & ~15; // mult of 16; NJC*chunk <= HW
    int j0 = sc * chunk;
    if (j0 >= nj) return;                            // uniform dead-chunk exit
    int j1 = min(j0 + chunk, nj);
    int t = threadIdx.x;
    int ci = blockIdx.x * 256 + t;
    // A preload: 64 floats as 16 v4 (amatR zero-padded past ni -> no clamps)
    const v4* Ar = (const v4*)(amatR + ((size_t)b * HW + ci) * C2);
    v4 A[16];
#pragma unroll
    for (int q = 0; q < 16; q++) A[q] = Ar[q];
    // staging: 1 v4 per thread per tile (256 thr x 16B = 4 KB tile)
    const float* Bb = bmatT + (size_t)b * C2 * HW;
    int src_c = t >> 2, src_col = (t & 3) * 4;
    const float* srcp = Bb + (size_t)src_c * HW + src_col;
    v4 pf = *(const v4*)(srcp + j0);                 // prefetch tile 0
    float best = -INFINITY; int bestjj = -1;
    int buf = 0;
    for (int jb = j0; jb < j1; jb += JTILE) {
        __syncthreads();                             // prev readers of Bs[buf] done
        *(v4*)&Bs[buf][src_c][src_col] = pf;         // (compiler waits vmcnt here)
        __syncthreads();
        int jn = jb + JTILE;
        if (jn < j1) pf = *(const v4*)(srcp + jn);   // prefetch next tile (async)
        v4 a0 = {0,0,0,0}, a1 = {0,0,0,0}, a2 = {0,0,0,0}, a3 = {0,0,0,0};
#pragma unroll
        for (int q = 0; q < 16; q++) {
#pragma unroll
            for (int r = 0; r < 4; r++) {
                float av = A[q][r];
                const v4* br = (const v4*)&Bs[buf][4 * q + r][0];  // uniform addr
                a0 += br[0] * av;  a1 += br[1] * av;
                a2 += br[2] * av;  a3 += br[3] * av;
            }
        }
        int lim = j1 - jb;                           // tail guard (padded cols = 0)
#define SEL(Q) { \
        if (Q*4+0 < lim && a##Q.x > best) { best = a##Q.x; bestjj = jb + Q*4+0; } \
        if (Q*4+1 < lim && a##Q.y > best) { best = a##Q.y; bestjj = jb + Q*4+1; } \
        if (Q*4+2 < lim && a##Q.z > best) { best = a##Q.z; bestjj = jb + Q*4+2; } \
        if (Q*4+3 < lim && a##Q.w > best) { best = a##Q.w; bestjj = jb + Q*4+3; } }
        SEL(0) SEL(1) SEL(2) SEL(3)
#undef SEL
        buf ^= 1;
    }
    if (ci < ni && bestjj >= 0) {
        unsigned long long key = ((unsigned long long)ordf(best) << 32) |
                                 (unsigned long long)(~(unsigned int)bestjj);
        atomicMax(&amax[(size_t)b * HW + ilist[ci]], key);   // keyed by ORIGINAL position
    }
}

// ---------------- kernel 4: fused epilogue (copy + decode + gather) -------
// out channels [0,128): passthrough copy of x (float4).
// out channels [128,192): shift = former at argmax j (0 where !flag).
__global__ void epilogue_kernel(const float4* __restrict__ x4, const float* __restrict__ x,
                                const int* __restrict__ mask,
                                const unsigned long long* __restrict__ amax,
                                const int* __restrict__ jlist, float4* __restrict__ out4) {
    const int q = HW / 4;                            // 2304
    int t = blockIdx.x * blockDim.x + threadIdx.x;   // 0 .. 2*192*q-1
    if (t >= 2 * 192 * q) return;
    int pos4 = t % q;
    int c = (t / q) % 192;
    int b = t / (192 * q);
    if (c < 128) {
        out4[t] = x4[((size_t)b * 128 + c) * q + pos4];
    } else {
        float4 v = make_float4(0.f, 0.f, 0.f, 0.f);
        float* vp = &v.x;
        int pos = pos4 * 4;
        const float* xf = x + (size_t)(b * 128 + (c - 128)) * HW;
#pragma unroll
        for (int k = 0; k < 4; k++) {
            int p = pos + k;
            if (mask[p] >= 1) {
                unsigned long long key = amax[(size_t)b * HW + p];
                int j = 0;                           // nj==0 -> argmax of all-NEG row = 0
                if (key != 0ull) j = jlist[(int)(~(unsigned int)key)];
                vp[k] = xf[j];
            }
        }
        out4[t] = v;
    }
}

extern "C" void kernel_launch(void* const* d_in, const int* in_sizes, int n_in,
                              void* d_out, int out_size, void* d_ws, size_t ws_size,
                              hipStream_t stream) {
    const float* x = (const float*)d_in[0];
    const int* mask = (const int*)d_in[1];
    float4* out4 = (float4*)d_out;

    // workspace: counts(0) | ilist(128) | jlist(+36864) | amax(+36864)
    //            | amatR(+147456) | bmatT(+4718592)   (all 128B-aligned)
    char* ws = (char*)d_ws;
    int*   counts = (int*)ws;
    int*   ilist  = (int*)(ws + 128);
    int*   jlist  = (int*)(ws + 128 + 36864);
    unsigned long long* amax = (unsigned long long*)(ws + 128 + 2 * 36864);      // 147456 B
    float* amatR  = (float*)(ws + 128 + 2 * 36864 + 147456);                     // 4718592 B
    float* bmatT  = (float*)(ws + 128 + 2 * 36864 + 147456 + 4718592);           // 4718592 B

    // 1) compaction
    compact_kernel<<<1, 256, 0, stream>>>(mask, ilist, jlist, counts);
    // 2) row-major compacted A + transposed normalized B (+ amax zeroing)
    buildab_kernel<<<(4 * HW + 255) / 256, 256, 0, stream>>>(x, ilist, jlist, counts,
                                                             amatR, bmatT, amax);
    // 3) broadcast-B GEMM + argmax: grid (i-blocks, j-chunks, batch)
    {
        dim3 grid(HW / 256, NJC, 2);                 // dead i-blocks/chunks exit early
        gemm_argmax_kernel<<<grid, 256, 0, stream>>>(amatR, bmatT, ilist, counts, amax);
    }
    // 4) fused copy + decode + gather
    {
        int n = 2 * 192 * (HW / 4);
        epilogue_kernel<<<(n + 255) / 256, 256, 0, stream>>>((const float4*)x, x, mask, amax, jlist, out4);
    }
}

// Round 11
// 173.595 us; speedup vs baseline: 3.1301x; 3.1301x over previous
//
#include <hip/hip_runtime.h>
#include <hip/hip_bf16.h>
#include <math.h>

#define HW 9216      // 96*96
#define C2 64
#define NJC 8        // j-chunk count (grid.y)
#define EPSN 1e-8f

typedef float v4 __attribute__((ext_vector_type(4)));

// ---------------- kernel 1: compaction (256 threads, shuffle scan) --------
// ilist = positions with mask>=1 (flagged i), jlist = positions with mask<1
__global__ void compact_kernel(const int* __restrict__ mask, int* __restrict__ ilist,
                               int* __restrict__ jlist, int* __restrict__ counts) {
    int t = threadIdx.x;                 // 0..255, each owns 36 consecutive positions
    int base = t * 36;
    unsigned long long fl = 0ull; int cnt = 0;
#pragma unroll
    for (int k = 0; k < 36; k++) {
        int f = (mask[base + k] >= 1) ? 1 : 0;
        fl |= (unsigned long long)f << k;
        cnt += f;
    }
    int lane = t & 63, wave = t >> 6;
    int v = cnt;
#pragma unroll
    for (int off = 1; off < 64; off <<= 1) {
        int u = __shfl_up(v, off, 64);
        if (lane >= off) v += u;
    }
    __shared__ int wsum[4];
    if (lane == 63) wsum[wave] = v;
    __syncthreads();
    int woff = 0;
#pragma unroll
    for (int w = 0; w < 4; w++) if (w < wave) woff += wsum[w];
    int incl = v + woff;
    int excl = incl - cnt;
    int posF = excl, posU = base - excl;
#pragma unroll
    for (int k = 0; k < 36; k++) {
        int p = base + k;
        if ((fl >> k) & 1ull) ilist[posF++] = p; else jlist[posU++] = p;
    }
    if (t == 255) { counts[0] = incl; counts[1] = HW - incl; }
}

// ---------------- kernel 2: build transposed compacted A and B ------------
// amatT[b][c][ci] = lat[b][c][ilist[ci]]                    (unnormalized)
// bmatT[b][c][jj] = lat[b][c][jlist[jj]] / max(||lat_j||,eps)
// zero-padded to HW columns so GEMM tiles read benign zeros. Also zeroes amax.
__global__ void buildab_kernel(const float* __restrict__ x, const int* __restrict__ ilist,
                               const int* __restrict__ jlist, const int* __restrict__ counts,
                               float* __restrict__ amatT, float* __restrict__ bmatT,
                               unsigned long long* __restrict__ amax) {
    int t = blockIdx.x * blockDim.x + threadIdx.x;   // 0 .. 4*HW-1
    if (t >= 4 * HW) return;
    if (t < 2 * HW) amax[t] = 0ull;                  // ws is poisoned 0xAA pre-launch
    int kind = t / (2 * HW);                         // 0 = A, 1 = B
    int r = t - kind * 2 * HW;
    int b = r / HW, p = r - b * HW;
    int n = kind ? counts[1] : counts[0];
    float v[C2];
    if (p < n) {
        int src = kind ? jlist[p] : ilist[p];
        const float* xl = x + (size_t)(b * 128 + 64) * HW + src;
        float ss = 0.f;
#pragma unroll
        for (int c = 0; c < C2; c++) { float w = xl[(size_t)c * HW]; v[c] = w; ss = fmaf(w, w, ss); }
        if (kind) {
            float inv = 1.0f / fmaxf(sqrtf(ss), EPSN);
#pragma unroll
            for (int c = 0; c < C2; c++) v[c] *= inv;
        }
    } else {
#pragma unroll
        for (int c = 0; c < C2; c++) v[c] = 0.f;
    }
    float* d = (kind ? bmatT : amatT) + (size_t)b * C2 * HW + p;
#pragma unroll
    for (int c = 0; c < C2; c++) d[(size_t)c * HW] = v[c];
}

// ordered-float mapping: monotone bijection float -> uint32 under unsigned compare
__device__ __forceinline__ unsigned int ordf(float f) {
    unsigned int u = __float_as_uint(f);
    return (u & 0x80000000u) ? ~u : (u | 0x80000000u);
}

// ---------------- kernel 3: LDS-tiled GEMM + argmax (B double-buffered) ---
// R8 structure (proven: VGPR 60, accs resident) + dbuf B staging. Block
// (256 thr) = 64i x 64j tile, lane owns 4x4 micro-tile. Per k: 2 ds_read_b128
// (A: 2-way aliased ~free; B: 4-addr broadcast ~free) + 16 v_fmac. B tile for
// t+1 prefetched into 4 v4 regs during compute of t -> barrier waits on wave
// skew, not VMEM. keys padded to [64][17] (R8's 1.38M conflicts were its
// stride-128B layout). First-max: ascending j, strict >, key=ord(v)<<32|~j.
__global__ __launch_bounds__(256, 4) void gemm_argmax_kernel(
    const float* __restrict__ amatT, const float* __restrict__ bmatT,
    const int* __restrict__ ilist, const int* __restrict__ counts,
    unsigned long long* __restrict__ amax)
{
    __shared__ float As[64][64];                     // 16 KB  [c][i]
    __shared__ float Bs[2][64][64];                  // 32 KB  [buf][c][j]
    __shared__ unsigned long long keys[64][17];      // 8.5 KB (padded: no conflicts)
    int b = blockIdx.z;
    int sc = blockIdx.y;
    int i0 = blockIdx.x * 64;
    int ni = counts[0], nj = counts[1];
    if (i0 >= ni) return;                            // uniform dead-block exit
    int jt_total = (nj + 63) >> 6;
    int tpc = (jt_total + NJC - 1) / NJC;
    int t0 = sc * tpc, t1 = min(t0 + tpc, jt_total);
    if (t0 >= t1) return;                            // uniform dead-chunk exit
    int t = threadIdx.x;
    int i4 = t & 15, j4 = t >> 4;
    // stage A once (coalesced float4; amatT zero-padded past ni)
    const float* Ab = amatT + (size_t)b * C2 * HW;
#pragma unroll
    for (int q = 0; q < 4; q++) {
        int idx = q * 256 + t;                       // 0..1023 float4 slots
        int c = idx >> 4, col4 = (idx & 15) * 4;
        *(v4*)&As[c][col4] = *(const v4*)&Ab[(size_t)c * HW + i0 + col4];
    }
    const float* Bb = bmatT + (size_t)b * C2 * HW;
    // prefetch B tile t0 into registers (4 x v4 per thread)
    v4 pf0, pf1, pf2, pf3;
    {
        int j0 = t0 * 64;
#pragma unroll
        for (int q = 0; q < 4; q++) {
            int idx = q * 256 + t;
            int c = idx >> 4, col4 = (idx & 15) * 4;
            v4 val = *(const v4*)&Bb[(size_t)c * HW + j0 + col4];
            if (q == 0) pf0 = val; else if (q == 1) pf1 = val;
            else if (q == 2) pf2 = val; else pf3 = val;
        }
    }
    float best0 = -INFINITY, best1 = -INFINITY, best2 = -INFINITY, best3 = -INFINITY;
    int bj0 = -1, bj1 = -1, bj2 = -1, bj3 = -1;
    int buf = 0;
    for (int tt = t0; tt < t1; ++tt, buf ^= 1) {
        // store prefetched tile into Bs[buf] (its prior readers finished
        // before the barrier of the previous iteration)
#pragma unroll
        for (int q = 0; q < 4; q++) {
            int idx = q * 256 + t;
            int c = idx >> 4, col4 = (idx & 15) * 4;
            v4 val = (q == 0) ? pf0 : (q == 1) ? pf1 : (q == 2) ? pf2 : pf3;
            *(v4*)&Bs[buf][c][col4] = val;
        }
        // issue next tile's loads (consumed next iteration -> latency hidden)
        if (tt + 1 < t1) {
            int jn = (tt + 1) * 64;
#pragma unroll
            for (int q = 0; q < 4; q++) {
                int idx = q * 256 + t;
                int c = idx >> 4, col4 = (idx & 15) * 4;
                v4 val = *(const v4*)&Bb[(size_t)c * HW + jn + col4];
                if (q == 0) pf0 = val; else if (q == 1) pf1 = val;
                else if (q == 2) pf2 = val; else pf3 = val;
            }
        }
        __syncthreads();                             // Bs[buf] writes visible (covers As on iter 0)
        v4 acc0 = {0.f,0.f,0.f,0.f}, acc1 = {0.f,0.f,0.f,0.f};
        v4 acc2 = {0.f,0.f,0.f,0.f}, acc3 = {0.f,0.f,0.f,0.f};
#pragma unroll 8
        for (int c = 0; c < 64; ++c) {
            v4 av = *(const v4*)&As[c][i4 * 4];      // rows 4*i4..+3
            v4 bv = *(const v4*)&Bs[buf][c][j4 * 4]; // cols 4*j4..+3 (broadcast)
            acc0 += bv * av.x;
            acc1 += bv * av.y;
            acc2 += bv * av.z;
            acc3 += bv * av.w;
        }
        __syncthreads();                             // compute done before next store to Bs[buf^1]? (skew guard)
        // selection over lane's 4 cols, ascending j, strict > (first-max)
        int jb = tt * 64 + j4 * 4;
#define SEL(R) { \
        if (jb + 0 < nj && acc##R.x > best##R) { best##R = acc##R.x; bj##R = jb + 0; } \
        if (jb + 1 < nj && acc##R.y > best##R) { best##R = acc##R.y; bj##R = jb + 1; } \
        if (jb + 2 < nj && acc##R.z > best##R) { best##R = acc##R.z; bj##R = jb + 2; } \
        if (jb + 3 < nj && acc##R.w > best##R) { best##R = acc##R.w; bj##R = jb + 3; } }
        SEL(0) SEL(1) SEL(2) SEL(3)
#undef SEL
    }
    // block-level reduce: keys[row][j4], then max over 16 j4 groups per row
#define KEY(B, J) ((J) >= 0 ? (((unsigned long long)ordf(B) << 32) | (unsigned long long)(~(unsigned)(J))) : 0ull)
    keys[i4 * 4 + 0][j4] = KEY(best0, bj0);
    keys[i4 * 4 + 1][j4] = KEY(best1, bj1);
    keys[i4 * 4 + 2][j4] = KEY(best2, bj2);
    keys[i4 * 4 + 3][j4] = KEY(best3, bj3);
#undef KEY
    __syncthreads();
    if (t < 64) {
        unsigned long long m = 0ull;
#pragma unroll
        for (int g = 0; g < 16; g++) { unsigned long long k = keys[t][g]; if (k > m) m = k; }
        int i = i0 + t;
        if (m != 0ull && i < ni)
            atomicMax(&amax[(size_t)b * HW + ilist[i]], m);  // keyed by ORIGINAL position
    }
}

// ---------------- kernel 4: fused epilogue (copy + decode + gather) -------
// out channels [0,128): passthrough copy of x (float4).
// out channels [128,192): shift = former at argmax j (0 where !flag).
__global__ void epilogue_kernel(const float4* __restrict__ x4, const float* __restrict__ x,
                                const int* __restrict__ mask,
                                const unsigned long long* __restrict__ amax,
                                const int* __restrict__ jlist, float4* __restrict__ out4) {
    const int q = HW / 4;                            // 2304
    int t = blockIdx.x * blockDim.x + threadIdx.x;   // 0 .. 2*192*q-1
    if (t >= 2 * 192 * q) return;
    int pos4 = t % q;
    int c = (t / q) % 192;
    int b = t / (192 * q);
    if (c < 128) {
        out4[t] = x4[((size_t)b * 128 + c) * q + pos4];
    } else {
        float4 v = make_float4(0.f, 0.f, 0.f, 0.f);
        float* vp = &v.x;
        int pos = pos4 * 4;
        const float* xf = x + (size_t)(b * 128 + (c - 128)) * HW;
#pragma unroll
        for (int k = 0; k < 4; k++) {
            int p = pos + k;
            if (mask[p] >= 1) {
                unsigned long long key = amax[(size_t)b * HW + p];
                int j = 0;                           // nj==0 -> argmax of all-NEG row = 0
                if (key != 0ull) j = jlist[(int)(~(unsigned int)key)];
                vp[k] = xf[j];
            }
        }
        out4[t] = v;
    }
}

extern "C" void kernel_launch(void* const* d_in, const int* in_sizes, int n_in,
                              void* d_out, int out_size, void* d_ws, size_t ws_size,
                              hipStream_t stream) {
    const float* x = (const float*)d_in[0];
    const int* mask = (const int*)d_in[1];
    float4* out4 = (float4*)d_out;

    // workspace: counts(0) | ilist(128) | jlist(+36864) | amax(+36864)
    //            | amatT(+147456) | bmatT(+4718592)   (all 128B-aligned)
    char* ws = (char*)d_ws;
    int*   counts = (int*)ws;
    int*   ilist  = (int*)(ws + 128);
    int*   jlist  = (int*)(ws + 128 + 36864);
    unsigned long long* amax = (unsigned long long*)(ws + 128 + 2 * 36864);      // 147456 B
    float* amatT  = (float*)(ws + 128 + 2 * 36864 + 147456);                     // 4718592 B
    float* bmatT  = (float*)(ws + 128 + 2 * 36864 + 147456 + 4718592);           // 4718592 B

    // 1) compaction
    compact_kernel<<<1, 256, 0, stream>>>(mask, ilist, jlist, counts);
    // 2) transposed compacted A + normalized B (+ amax zeroing)
    buildab_kernel<<<(4 * HW + 255) / 256, 256, 0, stream>>>(x, ilist, jlist, counts,
                                                             amatT, bmatT, amax);
    // 3) tiled GEMM + argmax: grid (i-tiles, j-chunks, batch)
    {
        dim3 grid(HW / 64, NJC, 2);                  // dead i-tiles exit early
        gemm_argmax_kernel<<<grid, 256, 0, stream>>>(amatT, bmatT, ilist, counts, amax);
    }
    // 4) fused copy + decode + gather
    {
        int n = 2 * 192 * (HW / 4);
        epilogue_kernel<<<(n + 255) / 256, 256, 0, stream>>>((const float4*)x, x, mask, amax, jlist, out4);
    }
}